// Round 1
// baseline (681.425 us; speedup 1.0000x reference)
//
#include <hip/hip_runtime.h>
#include <math.h>

typedef short bf16x8 __attribute__((ext_vector_type(8)));
typedef float floatx4 __attribute__((ext_vector_type(4)));

#define NC 192
#define HH 256
#define WSZ 8
#define NSHIFT 4
#define NHEADS 6

// LDS map (bytes):
//  region A [0, 26112): phase0 xstage (24576) / per-head qkvh f32[96][68] (26112)
//                       after frag pack: attnb f32[32][36] @0 (4608)
//  obuf  [26112, 35328): f32[64][36] (9216)   -- own region, no overlap with qkvh
//  frags [35328, 49664): 14 frags x 1024 B  (q:0-3, k:4-7, v:8-11, a:12-13)
#define QKVH_STRIDE 68
#define ATTN_STRIDE 36
#define OBUF_STRIDE 36
#define OBUF_OFF 26112
#define FRAG_OFF 35328
#define LDS_TOTAL 49664

#define QKV_FRAG_ELEMS (576 * 192)   // ws: qkv frags then proj frags (bf16)

__device__ __forceinline__ unsigned short f2bf(float f) {
    union { float f; unsigned int u; } v; v.f = f;
    unsigned int u = v.u + 0x7FFFu + ((v.u >> 16) & 1u);
    return (unsigned short)(u >> 16);
}

// ---- preprocess: swizzle qkv_w / proj_w (f32 row-major) into bf16 MFMA A-frags ----
// A-frag for tile (mt, kt): lane l, j in [0,8): A[mt*16 + (l&15)][kt*32 + (l>>4)*8 + j]
// stored at ws[((mt*6 + kt)*64 + l)*8 + j]
__global__ void preproc_kernel(const float* __restrict__ qkv_w,
                               const float* __restrict__ proj_w,
                               unsigned short* __restrict__ ws) {
    int e = blockIdx.x * 256 + threadIdx.x;
    if (e < QKV_FRAG_ELEMS) {
        int blk = e >> 9, l = (e >> 3) & 63, j = e & 7;
        int mt = blk / 6, kt = blk % 6;
        ws[e] = f2bf(qkv_w[(mt * 16 + (l & 15)) * NC + kt * 32 + (l >> 4) * 8 + j]);
    } else if (e < QKV_FRAG_ELEMS + NC * NC) {
        int e2 = e - QKV_FRAG_ELEMS;
        int blk = e2 >> 9, l = (e2 >> 3) & 63, j = e2 & 7;
        int mt = blk / 6, kt = blk % 6;
        ws[e] = f2bf(proj_w[(mt * 16 + (l & 15)) * NC + kt * 32 + (l >> 4) * 8 + j]);
    }
}

__global__ __launch_bounds__(256, 3) void attn_main(
    const float* __restrict__ x, const unsigned short* __restrict__ wsA,
    const float* __restrict__ dw_w, const float* __restrict__ temperature,
    float* __restrict__ out)
{
    __shared__ __align__(16) unsigned char smem[LDS_TOTAL];
    float* qkvh = (float*)smem;
    unsigned short* xstage = (unsigned short*)smem;
    float* attnb = (float*)smem;                       // [32][36]  (overlaps qkvh, dead by then)
    float* obuf  = (float*)(smem + OBUF_OFF);          // [64][36]
    unsigned short* frags = (unsigned short*)(smem + FRAG_OFF);

    const int t = threadIdx.x;
    const int lane = t & 63;
    const int wv = t >> 6;          // wave id == n-tile (16 px) owned by this wave
    const int quad = lane >> 4;
    const int l15 = lane & 15;
    const int blk = blockIdx.x;
    const int b = blk >> 10, wi = (blk >> 5) & 31, wj = blk & 31;

    // ---- stage x window (rolled -4) into B-frag layout, bf16; float4 global loads ----
    // groups of 4 px never cross the wrap (base ww ≡ 0 mod 4)
    for (int idx = t; idx < NC * 16; idx += 256) {
        int c = idx >> 4, r = (idx >> 1) & 7, s4 = idx & 1;
        int hh = (wi * WSZ + r + NSHIFT) & 255;
        int ww = (wj * WSZ + s4 * 4 + NSHIFT) & 255;
        float4 v4 = *((const float4*)(x + ((size_t)(b * NC + c) * HH + hh) * HH + ww));
        int kt = c >> 5, ko = c & 31;
        int p0 = r * 8 + s4 * 4;
        int fr = kt * 4 + (p0 >> 4);
        int lxb = ((ko >> 3) << 4) | (p0 & 15);
        unsigned short* dst = xstage + (fr * 64 + lxb) * 8 + (ko & 7);
        dst[0]  = f2bf(v4.x);
        dst[8]  = f2bf(v4.y);
        dst[16] = f2bf(v4.z);
        dst[24] = f2bf(v4.w);
    }
    __syncthreads();

    bf16x8 Bx[6];
    #pragma unroll
    for (int kt = 0; kt < 6; ++kt)
        Bx[kt] = *((const bf16x8*)(xstage + ((kt * 4 + wv) * 64 + lane) * 8));
    __syncthreads();   // xstage region free -> qkvh

    bf16x8 pB0, pB1, pB2, pB3, pB4, pB5;   // proj B-frags accumulated per head

    #pragma unroll 1
    for (int h = 0; h < NHEADS; ++h) {
        // ---- 1. qkv GEMM for head h: 6 m-tiles of 16 rows ----
        #pragma unroll
        for (int mtl = 0; mtl < 6; ++mtl) {
            int part = mtl >> 1, sub = mtl & 1;
            int mt_g = part * 12 + h * 2 + sub;
            const bf16x8* aptr = (const bf16x8*)wsA + (size_t)(mt_g * 6) * 64 + lane;
            floatx4 acc = {0.f, 0.f, 0.f, 0.f};
            #pragma unroll
            for (int kt = 0; kt < 6; ++kt) {
                bf16x8 a = aptr[kt * 64];
                acc = __builtin_amdgcn_mfma_f32_16x16x32_bf16(a, Bx[kt], acc, 0, 0, 0);
            }
            int rowbase = part * 32 + sub * 16 + quad * 4;
            int col = wv * 16 + l15;
            #pragma unroll
            for (int rg = 0; rg < 4; ++rg)
                qkvh[(rowbase + rg) * QKVH_STRIDE + col] = acc[rg];
        }
        __syncthreads();   // S1: qkvh visible

        // ---- 2. depthwise 3x3 + l2-norm + bf16 frag emit, all fused in registers ----
        if (t < 192) {
            int ch = t >> 1, half = t & 1;
            int part = ch >> 5;
            int g = part * NC + h * 32 + (ch & 31);
            const float* wp = dw_w + (size_t)g * 9;
            float w[9];
            #pragma unroll
            for (int i = 0; i < 9; ++i) w[i] = wp[i];
            const float* base = qkvh + ch * QKVH_STRIDE;
            int r0 = half * 4;
            float dwout[4][8];
            float ra[8], rb[8], rc[8];
            auto loadrow = [&](float* dst, int r2) {
                if ((unsigned)r2 < 8u) {
                    float4 lo = *((const float4*)(base + r2 * 8));
                    float4 hi = *((const float4*)(base + r2 * 8 + 4));
                    dst[0]=lo.x; dst[1]=lo.y; dst[2]=lo.z; dst[3]=lo.w;
                    dst[4]=hi.x; dst[5]=hi.y; dst[6]=hi.z; dst[7]=hi.w;
                } else {
                    #pragma unroll
                    for (int i = 0; i < 8; ++i) dst[i] = 0.f;
                }
            };
            auto conv3 = [&](float* o, const float* rm, const float* rz, const float* rp) {
                #pragma unroll
                for (int s = 0; s < 8; ++s) {
                    float acc = w[1]*rm[s] + w[4]*rz[s] + w[7]*rp[s];
                    if (s > 0) acc += w[0]*rm[s-1] + w[3]*rz[s-1] + w[6]*rp[s-1];
                    if (s < 7) acc += w[2]*rm[s+1] + w[5]*rz[s+1] + w[8]*rp[s+1];
                    o[s] = acc;
                }
            };
            loadrow(ra, r0 - 1); loadrow(rb, r0); loadrow(rc, r0 + 1);
            conv3(dwout[0], ra, rb, rc);
            loadrow(ra, r0 + 2); conv3(dwout[1], rb, rc, ra);
            loadrow(rb, r0 + 3); conv3(dwout[2], rc, ra, rb);
            loadrow(rc, r0 + 4); conv3(dwout[3], ra, rb, rc);

            // row sum-of-squares: this thread has 32 px, partner (t^1) has the other 32
            float ss = 0.f;
            #pragma unroll
            for (int ro = 0; ro < 4; ++ro)
                #pragma unroll
                for (int s = 0; s < 8; ++s) ss += dwout[ro][s] * dwout[ro][s];
            ss += __shfl_xor(ss, 1, 64);
            float sc = 1.0f / fmaxf(sqrtf(ss), 1e-12f);

            if (part < 2) {
                // q/k frag: fragid = part*4 + mt*2 + half; lane (ro*16 + ch&15), elems s
                int mt = (ch & 31) >> 4;
                int fid = part * 4 + mt * 2 + half;
                unsigned short* fb = frags + fid * 512 + (ch & 15) * 8;
                #pragma unroll
                for (int ro = 0; ro < 4; ++ro) {
                    bf16x8 o;
                    #pragma unroll
                    for (int s = 0; s < 8; ++s) o[s] = (short)f2bf(dwout[ro][s] * sc);
                    *((bf16x8*)(fb + ro * 128)) = o;   // (ro*16)*8 = 128 ushorts
                }
            } else {
                // v frag scatter: value(ch, px) -> frag(8 + px>>4), lane ((chv>>3)*16 | px&15), elem chv&7
                int chv = ch & 31;
                int quad_t = chv >> 3, j = chv & 7;
                #pragma unroll
                for (int ro = 0; ro < 4; ++ro) {
                    int fid = 8 + half * 2 + (ro >> 1);
                    int l15b = (ro & 1) * 8;
                    unsigned short* fb = frags + fid * 512 + ((quad_t << 4) | l15b) * 8 + j;
                    #pragma unroll
                    for (int s = 0; s < 8; ++s)
                        fb[s * 8] = f2bf(dwout[ro][s]);
                }
            }
        }
        __syncthreads();   // S2: frags ready; qkvh region dead

        // ---- 3. QK^T (one 16x16 tile per wave) ----
        {
            int mt = wv >> 1, ntk = wv & 1;
            floatx4 acc = {0.f, 0.f, 0.f, 0.f};
            #pragma unroll
            for (int kt = 0; kt < 2; ++kt) {
                bf16x8 aq = *((const bf16x8*)(frags + (mt * 2 + kt) * 512 + lane * 8));
                bf16x8 bk = *((const bf16x8*)(frags + (4 + ntk * 2 + kt) * 512 + lane * 8));
                acc = __builtin_amdgcn_mfma_f32_16x16x32_bf16(aq, bk, acc, 0, 0, 0);
            }
            float tmp = temperature[h];
            #pragma unroll
            for (int rg = 0; rg < 4; ++rg)
                attnb[(mt * 16 + quad * 4 + rg) * ATTN_STRIDE + ntk * 16 + l15] = acc[rg] * tmp;
        }
        __syncthreads();   // S3

        // ---- 4. softmax + A-frag emit (threads 0..127: row = t>>2, slice = t&3) ----
        if (t < 128) {
            int row = t >> 2, sl = t & 3;
            const float* src = attnb + row * ATTN_STRIDE + sl * 8;
            float4 lo = *((const float4*)src), hi = *((const float4*)(src + 4));
            float v[8] = {lo.x, lo.y, lo.z, lo.w, hi.x, hi.y, hi.z, hi.w};
            float mx = v[0];
            #pragma unroll
            for (int i = 1; i < 8; ++i) mx = fmaxf(mx, v[i]);
            mx = fmaxf(mx, __shfl_xor(mx, 1, 64));
            mx = fmaxf(mx, __shfl_xor(mx, 2, 64));
            float sum = 0.f;
            #pragma unroll
            for (int i = 0; i < 8; ++i) { v[i] = __expf(v[i] - mx); sum += v[i]; }
            sum += __shfl_xor(sum, 1, 64);
            sum += __shfl_xor(sum, 2, 64);
            float inv = 1.0f / sum;
            bf16x8 o;
            #pragma unroll
            for (int i = 0; i < 8; ++i) o[i] = (short)f2bf(v[i] * inv);
            *((bf16x8*)(frags + (12 + (row >> 4)) * 512 + (sl * 16 + (row & 15)) * 8)) = o;
        }
        __syncthreads();   // S4

        // ---- 5. attn @ V -> obuf[px][ch] ----
        {
            bf16x8 bv = *((const bf16x8*)(frags + (8 + wv) * 512 + lane * 8));
            #pragma unroll
            for (int mt = 0; mt < 2; ++mt) {
                bf16x8 aa = *((const bf16x8*)(frags + (12 + mt) * 512 + lane * 8));
                floatx4 acc = {0.f, 0.f, 0.f, 0.f};
                acc = __builtin_amdgcn_mfma_f32_16x16x32_bf16(aa, bv, acc, 0, 0, 0);
                #pragma unroll
                for (int rg = 0; rg < 4; ++rg)
                    obuf[(wv * 16 + l15) * OBUF_STRIDE + mt * 16 + quad * 4 + rg] = acc[rg];
            }
        }
        __syncthreads();   // S5

        // ---- 6. pack O into this wave's proj B-frag (kt = h); no trailing barrier:
        //         obuf is in its own region, next head's qkvh writes don't touch it ----
        {
            const float* src = obuf + (wv * 16 + l15) * OBUF_STRIDE + quad * 8;
            float4 lo = *((const float4*)src), hi = *((const float4*)(src + 4));
            float v[8] = {lo.x, lo.y, lo.z, lo.w, hi.x, hi.y, hi.z, hi.w};
            bf16x8 o;
            #pragma unroll
            for (int i = 0; i < 8; ++i) o[i] = (short)f2bf(v[i]);
            switch (h) {
                case 0: pB0 = o; break;
                case 1: pB1 = o; break;
                case 2: pB2 = o; break;
                case 3: pB3 = o; break;
                case 4: pB4 = o; break;
                default: pB5 = o; break;
            }
        }
    }

    // ---- proj GEMM: 12 m-tiles, nt = wv; direct global store (roll +4) ----
    const bf16x8* apro = (const bf16x8*)(wsA + QKV_FRAG_ELEMS);
    int px = wv * 16 + l15;
    int r = px >> 3, s = px & 7;
    int hh = (wi * WSZ + r + NSHIFT) & 255;
    int ww = (wj * WSZ + s + NSHIFT) & 255;
    #pragma unroll
    for (int mt = 0; mt < 12; ++mt) {
        const bf16x8* ap = apro + (size_t)(mt * 6) * 64 + lane;
        floatx4 acc = {0.f, 0.f, 0.f, 0.f};
        acc = __builtin_amdgcn_mfma_f32_16x16x32_bf16(ap[0 * 64], pB0, acc, 0, 0, 0);
        acc = __builtin_amdgcn_mfma_f32_16x16x32_bf16(ap[1 * 64], pB1, acc, 0, 0, 0);
        acc = __builtin_amdgcn_mfma_f32_16x16x32_bf16(ap[2 * 64], pB2, acc, 0, 0, 0);
        acc = __builtin_amdgcn_mfma_f32_16x16x32_bf16(ap[3 * 64], pB3, acc, 0, 0, 0);
        acc = __builtin_amdgcn_mfma_f32_16x16x32_bf16(ap[4 * 64], pB4, acc, 0, 0, 0);
        acc = __builtin_amdgcn_mfma_f32_16x16x32_bf16(ap[5 * 64], pB5, acc, 0, 0, 0);
        int chb = mt * 16 + quad * 4;
        #pragma unroll
        for (int rg = 0; rg < 4; ++rg)
            out[((size_t)(b * NC + chb + rg) * HH + hh) * HH + ww] = acc[rg];
    }
}

extern "C" void kernel_launch(void* const* d_in, const int* in_sizes, int n_in,
                              void* d_out, int out_size, void* d_ws, size_t ws_size,
                              hipStream_t stream) {
    const float* x           = (const float*)d_in[0];
    const float* qkv_w       = (const float*)d_in[1];
    const float* dw_w        = (const float*)d_in[2];
    const float* proj_w      = (const float*)d_in[3];
    const float* temperature = (const float*)d_in[4];
    float* out = (float*)d_out;
    unsigned short* wsA = (unsigned short*)d_ws;

    // swizzle weights to bf16 MFMA A-fragments (runs every call; ~150K elems)
    int total = QKV_FRAG_ELEMS + NC * NC;
    hipLaunchKernelGGL(preproc_kernel, dim3((total + 255) / 256), dim3(256), 0, stream,
                       qkv_w, proj_w, wsA);
    hipLaunchKernelGGL(attn_main, dim3(4 * 32 * 32), dim3(256), 0, stream,
                       x, wsA, dw_w, temperature, out);
}